// Round 1
// baseline (446.641 us; speedup 1.0000x reference)
//
#include <hip/hip_runtime.h>
#include <hip/hip_bf16.h>
#include <stdint.h>

#define N 8192
#define D 128
#define NCHUNK 16
#define CHUNK (N / NCHUNK)      // 512 cols per chunk
#define RT 128                  // rows per block (4 waves x 32)
#define CT 64                   // cols per tile
#define NTILES (CHUNK / CT)     // 8
#define NBLK (N / RT * NCHUNK)  // 1024 main blocks

typedef short bf16x8 __attribute__((ext_vector_type(8)));
typedef float f32x4 __attribute__((ext_vector_type(4)));
typedef int   i32x4 __attribute__((ext_vector_type(4)));
typedef unsigned int uint32;

// ---- workspace layout (bytes) ----
#define OFF_ACC   0u                          // [0] float S_sum, [4] uint32 C_count
#define OFF_SQ2   1024u                       // 8192 floats
#define OFF_BCNT  (OFF_SQ2 + N * 4u)          // NBLK uint32 per-block negative counts
#define OFF_M     (OFF_BCNT + NBLK * 4u)      // NCHUNK*N floats (per-chunk row max)
#define OFF_L     (OFF_M + NCHUNK * N * 4u)
#define OFF_S     (OFF_L + NCHUNK * N * 4u)
#define OFF_F1    (OFF_S + NCHUNK * N * 4u)   // feat1 bf16
#define OFF_F2    (OFF_F1 + N * D * 2u)       // feat2 bf16

// Convert feats to bf16; compute sq2[j] = ||feat2_j||^2.
__global__ __launch_bounds__(256)
void prep_kernel(const float* __restrict__ f1, const float* __restrict__ f2,
                 unsigned short* __restrict__ f1b, unsigned short* __restrict__ f2b,
                 float* __restrict__ sq2) {
    const int w    = blockIdx.x * 4 + (threadIdx.x >> 6);  // 0..1023
    const int lane = threadIdx.x & 63;
    for (int row = w; row < N; row += 1024) {
        float a0 = f1[row * D + lane];
        float a1 = f1[row * D + 64 + lane];
        float b0 = f2[row * D + lane];
        float b1 = f2[row * D + 64 + lane];
        __hip_bfloat16 t;
        t = __float2bfloat16(a0); f1b[row * D + lane]      = *(unsigned short*)&t;
        t = __float2bfloat16(a1); f1b[row * D + 64 + lane] = *(unsigned short*)&t;
        t = __float2bfloat16(b0); f2b[row * D + lane]      = *(unsigned short*)&t;
        t = __float2bfloat16(b1); f2b[row * D + 64 + lane] = *(unsigned short*)&t;
        float ss = b0 * b0 + b1 * b1;
        #pragma unroll
        for (int off = 32; off > 0; off >>= 1) ss += __shfl_xor(ss, off);
        if (lane == 0) sq2[row] = ss;
    }
}

// FUSED: GEMM + online softmax + raw-simi masking + negative count.
// BARRIER-FREE main loop: the LDS B-staging (and both per-tile __syncthreads,
// whose implicit vmcnt(0) drains serialized the block and emptied the VMEM
// pipe during every compute phase) is deleted. B fragments are read directly
// from f2b, which is L1/L2-resident (16 KB slice per block-tile; first wave
// misses to L2, waves 2-4 hit L1 -> memory-side traffic identical to the
// staged version). Lane lo owns global cols 4*lo+cf — the same column
// mapping the old LDS permutation c(q)=4*(q&15)+(q>>4) produced — so the
// one-int4-per-row simi loads and f32x4 sq2 loads are unchanged.
// With no barriers, every resident wave free-runs with its 8 KB of simi
// loads in flight (~100 KB/CU >> ~22 KB/CU bandwidth-delay product), keeping
// HBM saturated through MFMA+softmax. simi loads are non-temporal so the
// 268 MB stream doesn't evict f2b from L2.
__global__ __launch_bounds__(256)
void main_kernel(const unsigned short* __restrict__ f1b,
                 const unsigned short* __restrict__ f2b,
                 const float* __restrict__ sq2,
                 const int* __restrict__ simi,
                 float* __restrict__ pm, float* __restrict__ pl, float* __restrict__ ps,
                 uint32* __restrict__ blockcnt) {
    __shared__ uint32 cred[4];

    const int tid  = threadIdx.x;
    const int wave = tid >> 6;
    const int lane = tid & 63;
    const int lo   = lane & 15;
    const int hi   = lane >> 4;

    const int rowtile = blockIdx.x;       // 0..63
    const int chunk   = blockIdx.y;       // 0..15
    const int rbase   = rowtile * RT + wave * 32;
    const int cbase0  = chunk * CHUNK;

    // A fragments: 2 sets of 16 rows, full K=128, resident for the sweep.
    bf16x8 afrag[2][4];
    #pragma unroll
    for (int a = 0; a < 2; a++) {
        const unsigned short* ap = f1b + (size_t)(rbase + a * 16 + lo) * D + hi * 8;
        #pragma unroll
        for (int kk = 0; kk < 4; kk++)
            afrag[a][kk] = *reinterpret_cast<const bf16x8*>(ap + kk * 32);
    }

    // simi pointer: rows rbase+hi*4 (+a*16+r), cols cbase0 + 4*lo
    const int* simi_p = simi + (size_t)(rbase + hi * 4) * N + cbase0 + 4 * lo;
    // B fragment pointer: lane (lo,hi) reads col cbase0+4*lo+cf, k=(kk*4+hi)*8
    const unsigned short* bp = f2b + (size_t)(cbase0 + 4 * lo) * D + hi * 8;

    // per-lane online-softmax state; negative count
    float m[2][4], l[2][4], s[2][4];
    #pragma unroll
    for (int a = 0; a < 2; a++)
        #pragma unroll
        for (int r = 0; r < 4; r++) { m[a][r] = -1e30f; l[a][r] = 0.f; s[a][r] = 0.f; }
    uint32 cnt = 0;

    for (int t = 0; t < NTILES; t++) {
        // simi loads issued first: they stream from HBM while the MFMAs run
        // on low-latency L1/L2-resident B fragments; consumed only at the
        // masked-sum at the bottom of the tile.
        i32x4 mkv[2][4];
        #pragma unroll
        for (int a = 0; a < 2; a++)
            #pragma unroll
            for (int r = 0; r < 4; r++)
                mkv[a][r] = __builtin_nontemporal_load(
                    reinterpret_cast<const i32x4*>(simi_p + (size_t)(a * 16 + r) * N));

        // MFMA: 32 rows x 64 cols; each B fragment feeds both A sets
        f32x4 acc[2][4];
        #pragma unroll
        for (int cf = 0; cf < 4; cf++) {
            acc[0][cf] = (f32x4){0.f, 0.f, 0.f, 0.f};
            acc[1][cf] = (f32x4){0.f, 0.f, 0.f, 0.f};
            #pragma unroll
            for (int kk = 0; kk < 4; kk++) {
                bf16x8 b = *reinterpret_cast<const bf16x8*>(bp + (size_t)cf * D + kk * 32);
                acc[0][cf] = __builtin_amdgcn_mfma_f32_16x16x32_bf16(afrag[0][kk], b, acc[0][cf], 0, 0, 0);
                acc[1][cf] = __builtin_amdgcn_mfma_f32_16x16x32_bf16(afrag[1][kk], b, acc[1][cf], 0, 0, 0);
            }
        }

        // convert raw masks to nibbles + count negatives
        uint32 mb[2][4];
        #pragma unroll
        for (int a = 0; a < 2; a++)
            #pragma unroll
            for (int r = 0; r < 4; r++) {
                i32x4 v = mkv[a][r];
                uint32 nib = (uint32)(v[0] == 1) | ((uint32)(v[1] == 1) << 1) |
                             ((uint32)(v[2] == 1) << 2) | ((uint32)(v[3] == 1) << 3);
                mb[a][r] = nib;
                cnt += 4u - __popc(nib);
            }

        // logits lg = 2c - sq2[col] (row-constant sq1 dropped); per-lane
        // online max + rescale + accumulate — no cross-lane ops in the loop
        f32x4 sqv = *reinterpret_cast<const f32x4*>(sq2 + cbase0 + t * CT + 4 * lo);
        #pragma unroll
        for (int a = 0; a < 2; a++)
            #pragma unroll
            for (int r = 0; r < 4; r++) {
                float lg[4];
                #pragma unroll
                for (int cf = 0; cf < 4; cf++)
                    lg[cf] = 2.0f * acc[a][cf][r] - sqv[cf];
                float tm = fmaxf(fmaxf(lg[0], lg[1]), fmaxf(lg[2], lg[3]));
                float mn = fmaxf(m[a][r], tm);
                float al = __expf(m[a][r] - mn);
                m[a][r] = mn;
                float p[4];
                #pragma unroll
                for (int cf = 0; cf < 4; cf++) p[cf] = __expf(lg[cf] - mn);
                l[a][r] = l[a][r] * al + ((p[0] + p[1]) + (p[2] + p[3]));
                float sm = 0.f;
                #pragma unroll
                for (int cf = 0; cf < 4; cf++)
                    sm += ((mb[a][r] >> cf) & 1u) ? p[cf] : 0.f;
                s[a][r] = s[a][r] * al + sm;
            }
        simi_p += CT;
        bp += (size_t)CT * D;
    }

    // end: cross-lane (lo group, 16 lanes) max + rescale + sum, once
    #pragma unroll
    for (int a = 0; a < 2; a++)
        #pragma unroll
        for (int r = 0; r < 4; r++) {
            float M = m[a][r];
            #pragma unroll
            for (int off = 1; off < 16; off <<= 1)
                M = fmaxf(M, __shfl_xor(M, off));
            float sc = __expf(m[a][r] - M);
            float L = l[a][r] * sc, S = s[a][r] * sc;
            #pragma unroll
            for (int off = 1; off < 16; off <<= 1) {
                L += __shfl_xor(L, off);
                S += __shfl_xor(S, off);
            }
            if (lo == 0) {
                int row = rbase + a * 16 + hi * 4 + r;
                int idx = chunk * N + row;
                pm[idx] = M; pl[idx] = L; ps[idx] = S;
            }
        }

    // negative count: wave reduce -> LDS -> one plain store per block
    #pragma unroll
    for (int off = 1; off < 64; off <<= 1) cnt += __shfl_xor(cnt, off);
    if (lane == 0) cred[wave] = cnt;
    __syncthreads();
    if (tid == 0)
        blockcnt[blockIdx.y * 64 + blockIdx.x] = cred[0] + cred[1] + cred[2] + cred[3];
}

// Merge per-chunk (m,l,s) partials per row; accumulate sum of s/l and the
// negative count (from 1024 per-block partials). 64 atomics total.
__global__ void merge_kernel(const float* __restrict__ pm, const float* __restrict__ pl,
                             const float* __restrict__ ps, const uint32* __restrict__ blockcnt,
                             float* __restrict__ s_acc, uint32* __restrict__ neg_acc) {
    const int row = blockIdx.x * 256 + threadIdx.x;
    float M = -1e30f;
    #pragma unroll
    for (int k = 0; k < NCHUNK; k++) M = fmaxf(M, pm[k * N + row]);
    float L = 0.f, S = 0.f;
    #pragma unroll
    for (int k = 0; k < NCHUNK; k++) {
        float e = __expf(pm[k * N + row] - M);
        L += pl[k * N + row] * e;
        S += ps[k * N + row] * e;
    }
    float r = S / L;
    uint32 pc = (threadIdx.x < 32) ? blockcnt[blockIdx.x * 32 + threadIdx.x] : 0u;
    #pragma unroll
    for (int off = 32; off > 0; off >>= 1) {
        r  += __shfl_xor(r, off);
        pc += __shfl_xor(pc, off);
    }
    __shared__ float red[4];
    __shared__ uint32 redp[4];
    int lane = threadIdx.x & 63, w = threadIdx.x >> 6;
    if (lane == 0) { red[w] = r; redp[w] = pc; }
    __syncthreads();
    if (threadIdx.x == 0) {
        atomicAdd(s_acc, red[0] + red[1] + red[2] + red[3]);
        atomicAdd(neg_acc, redp[0] + redp[1] + redp[2] + redp[3]);
    }
}

__global__ void final_kernel(const float* __restrict__ s_acc, const uint32* __restrict__ neg_acc,
                             float* __restrict__ out) {
    double S = (double)s_acc[0];
    double C = (double)neg_acc[0];   // count(simi != 1), counted directly
    double n = (double)N;
    out[0] = (float)((2.0 * S + C - n) / (n * n));
}

extern "C" void kernel_launch(void* const* d_in, const int* in_sizes, int n_in,
                              void* d_out, int out_size, void* d_ws, size_t ws_size,
                              hipStream_t stream) {
    const float* f1   = (const float*)d_in[0];
    const float* f2   = (const float*)d_in[1];
    const int*   simi = (const int*)d_in[2];
    float* out = (float*)d_out;
    char* ws = (char*)d_ws;

    float*  acc_s    = (float*)(ws + OFF_ACC);
    uint32* acc_n    = (uint32*)(ws + OFF_ACC + 4);
    float*  sq2      = (float*)(ws + OFF_SQ2);
    uint32* blockcnt = (uint32*)(ws + OFF_BCNT);
    float*  pm       = (float*)(ws + OFF_M);
    float*  pl       = (float*)(ws + OFF_L);
    float*  ps       = (float*)(ws + OFF_S);
    unsigned short* f1b = (unsigned short*)(ws + OFF_F1);
    unsigned short* f2b = (unsigned short*)(ws + OFF_F2);

    hipMemsetAsync(ws + OFF_ACC, 0, 64, stream);
    prep_kernel<<<256, 256, 0, stream>>>(f1, f2, f1b, f2b, sq2);
    main_kernel<<<dim3(N / RT, NCHUNK), 256, 0, stream>>>(f1b, f2b, sq2, simi,
                                                          pm, pl, ps, blockcnt);
    merge_kernel<<<N / 256, 256, 0, stream>>>(pm, pl, ps, blockcnt, acc_s, acc_n);
    final_kernel<<<1, 1, 0, stream>>>(acc_s, acc_n, out);
}

// Round 2
// 390.501 us; speedup vs baseline: 1.1438x; 1.1438x over previous
//
#include <hip/hip_runtime.h>
#include <hip/hip_bf16.h>
#include <stdint.h>

#define N 8192
#define D 128
#define NCHUNK 16
#define CHUNK (N / NCHUNK)      // 512 cols per chunk
#define RT 128                  // rows per block (4 waves x 32)
#define CT 64                   // cols per LDS tile
#define NTILES (CHUNK / CT)     // 8
#define NBLK (N / RT * NCHUNK)  // 1024 main blocks

typedef short bf16x8 __attribute__((ext_vector_type(8)));
typedef float f32x4 __attribute__((ext_vector_type(4)));
typedef int   i32x4 __attribute__((ext_vector_type(4)));
typedef unsigned int uint32;

// ---- workspace layout (bytes) ----
#define OFF_ACC   0u                          // [0] float S_sum, [4] uint32 C_count
#define OFF_SQ2   1024u                       // 8192 floats
#define OFF_BCNT  (OFF_SQ2 + N * 4u)          // NBLK uint32 per-block negative counts
#define OFF_M     (OFF_BCNT + NBLK * 4u)      // NCHUNK*N floats (per-chunk row max)
#define OFF_L     (OFF_M + NCHUNK * N * 4u)
#define OFF_S     (OFF_L + NCHUNK * N * 4u)
#define OFF_F1    (OFF_S + NCHUNK * N * 4u)   // feat1 bf16
#define OFF_F2    (OFF_F1 + N * D * 2u)       // feat2 bf16

// Convert feats to bf16; compute sq2[j] = ||feat2_j||^2.
__global__ __launch_bounds__(256)
void prep_kernel(const float* __restrict__ f1, const float* __restrict__ f2,
                 unsigned short* __restrict__ f1b, unsigned short* __restrict__ f2b,
                 float* __restrict__ sq2) {
    const int w    = blockIdx.x * 4 + (threadIdx.x >> 6);  // 0..1023
    const int lane = threadIdx.x & 63;
    for (int row = w; row < N; row += 1024) {
        float a0 = f1[row * D + lane];
        float a1 = f1[row * D + 64 + lane];
        float b0 = f2[row * D + lane];
        float b1 = f2[row * D + 64 + lane];
        __hip_bfloat16 t;
        t = __float2bfloat16(a0); f1b[row * D + lane]      = *(unsigned short*)&t;
        t = __float2bfloat16(a1); f1b[row * D + 64 + lane] = *(unsigned short*)&t;
        t = __float2bfloat16(b0); f2b[row * D + lane]      = *(unsigned short*)&t;
        t = __float2bfloat16(b1); f2b[row * D + 64 + lane] = *(unsigned short*)&t;
        float ss = b0 * b0 + b1 * b1;
        #pragma unroll
        for (int off = 32; off > 0; off >>= 1) ss += __shfl_xor(ss, off);
        if (lane == 0) sq2[row] = ss;
    }
}

// FUSED: GEMM + online softmax + raw-simi masking + negative count.
// R2: LDS staging restored (R1's direct-global B loads serialized every MFMA
// behind the earlier-issued simi HBM loads — vmcnt retires IN ISSUE ORDER).
// Now DOUBLE-BUFFERED LDS with ONE barrier per tile and all waits covered:
//   1. issue simi loads (tile t)          — consumed at step 4
//   2. issue staging loads (tile t+1)     — consumed at step 6
//   3. ds_read + 32 MFMAs from buf[cur]   — lgkmcnt only, no VMEM waits
//   4. convert simi -> nibbles            — vmcnt(4): simi oldest, covered by (3)
//   5. softmax VALU
//   6. ds_write staged regs -> buf[cur^1] — vmcnt(0) covered by (3)+(5)
//   7. __syncthreads                      — nothing outstanding: drain is free
// Double-buffering makes one barrier/tile race-free: buf[cur] reads land in
// registers before the barrier; buf[cur^1] was last read a full barrier ago.
// sched_barrier(0) after the MFMA cluster keeps the simi vmcnt wait below it.
__global__ __launch_bounds__(256)
void main_kernel(const unsigned short* __restrict__ f1b,
                 const unsigned short* __restrict__ f2b,
                 const float* __restrict__ sq2,
                 const int* __restrict__ simi,
                 float* __restrict__ pm, float* __restrict__ pl, float* __restrict__ ps,
                 uint32* __restrict__ blockcnt) {
    __shared__ unsigned short ldsB[2][CT * D];  // 2 x 16 KB, XOR-swizzled
    __shared__ uint32 cred[4];

    const int tid  = threadIdx.x;
    const int wave = tid >> 6;
    const int lane = tid & 63;
    const int lo   = lane & 15;
    const int hi   = lane >> 4;

    const int rowtile = blockIdx.x;       // 0..63
    const int chunk   = blockIdx.y;       // 0..15
    const int rbase   = rowtile * RT + wave * 32;
    const int cbase0  = chunk * CHUNK;

    // A fragments: 2 sets of 16 rows, full K=128, resident for the sweep.
    bf16x8 afrag[2][4];
    #pragma unroll
    for (int a = 0; a < 2; a++) {
        const unsigned short* ap = f1b + (size_t)(rbase + a * 16 + lo) * D + hi * 8;
        #pragma unroll
        for (int kk = 0; kk < 4; kk++)
            afrag[a][kk] = *reinterpret_cast<const bf16x8*>(ap + kk * 32);
    }

    const int sq_ = (tid >> 4);           // staging: position within 16-group
    const int sg_ = tid & 15;             // staging: 16B chunk index

    // simi pointer: rows rbase+hi*4 (+a*16+r), cols cbase0 + 4*lo
    const int* simi_p = simi + (size_t)(rbase + hi * 4) * N + cbase0 + 4 * lo;

    // per-lane online-softmax state; negative count
    float m[2][4], l[2][4], s[2][4];
    #pragma unroll
    for (int a = 0; a < 2; a++)
        #pragma unroll
        for (int r = 0; r < 4; r++) { m[a][r] = -1e30f; l[a][r] = 0.f; s[a][r] = 0.f; }
    uint32 cnt = 0;

    // prologue: stage tile 0 into buf 0
    #pragma unroll
    for (int it = 0; it < 4; it++) {
        int q = it * 16 + sq_;
        int c = 4 * (q & 15) + (q >> 4);
        uint4 v = *reinterpret_cast<const uint4*>(f2b + (size_t)(cbase0 + c) * D + sg_ * 8);
        *reinterpret_cast<uint4*>(&ldsB[0][q * D + ((sg_ ^ (q & 15)) * 8)]) = v;
    }
    __syncthreads();

    for (int t = 0; t < NTILES; t++) {
        const int cur = t & 1;

        // 1. simi loads (HBM stream, nontemporal) — oldest in the vmcnt queue,
        //    so the convert's wait leaves the staging loads outstanding.
        i32x4 mkv[2][4];
        #pragma unroll
        for (int a = 0; a < 2; a++)
            #pragma unroll
            for (int r = 0; r < 4; r++)
                mkv[a][r] = __builtin_nontemporal_load(
                    reinterpret_cast<const i32x4*>(simi_p + (size_t)(a * 16 + r) * N));

        // 2. staging loads for tile t+1 into registers
        uint4 stg[4];
        if (t < NTILES - 1) {
            const int cb_n = cbase0 + (t + 1) * CT;
            #pragma unroll
            for (int it = 0; it < 4; it++) {
                int q = it * 16 + sq_;
                int c = 4 * (q & 15) + (q >> 4);
                stg[it] = *reinterpret_cast<const uint4*>(
                    f2b + (size_t)(cb_n + c) * D + sg_ * 8);
            }
        }

        // 3. MFMA: 32 rows x 64 cols from buf[cur]; each B frag feeds both A sets
        f32x4 acc[2][4];
        #pragma unroll
        for (int cf = 0; cf < 4; cf++) {
            acc[0][cf] = (f32x4){0.f, 0.f, 0.f, 0.f};
            acc[1][cf] = (f32x4){0.f, 0.f, 0.f, 0.f};
            const int brow = cf * 16 + lo;
            #pragma unroll
            for (int kk = 0; kk < 4; kk++) {
                int g = kk * 4 + hi;
                bf16x8 b = *reinterpret_cast<const bf16x8*>(
                    &ldsB[cur][brow * D + ((g ^ (brow & 15)) * 8)]);
                acc[0][cf] = __builtin_amdgcn_mfma_f32_16x16x32_bf16(afrag[0][kk], b, acc[0][cf], 0, 0, 0);
                acc[1][cf] = __builtin_amdgcn_mfma_f32_16x16x32_bf16(afrag[1][kk], b, acc[1][cf], 0, 0, 0);
            }
        }
        // keep the simi-consuming vmcnt wait below the MFMA cluster
        __builtin_amdgcn_sched_barrier(0);

        // 4. convert raw masks to nibbles + count negatives
        uint32 mb[2][4];
        #pragma unroll
        for (int a = 0; a < 2; a++)
            #pragma unroll
            for (int r = 0; r < 4; r++) {
                i32x4 v = mkv[a][r];
                uint32 nib = (uint32)(v[0] == 1) | ((uint32)(v[1] == 1) << 1) |
                             ((uint32)(v[2] == 1) << 2) | ((uint32)(v[3] == 1) << 3);
                mb[a][r] = nib;
                cnt += 4u - __popc(nib);
            }

        // 5. logits lg = 2c - sq2[col] (row-constant sq1 dropped); per-lane
        //    online max + rescale + accumulate — no cross-lane ops in the loop
        f32x4 sqv = *reinterpret_cast<const f32x4*>(sq2 + cbase0 + t * CT + 4 * lo);
        #pragma unroll
        for (int a = 0; a < 2; a++)
            #pragma unroll
            for (int r = 0; r < 4; r++) {
                float lg[4];
                #pragma unroll
                for (int cf = 0; cf < 4; cf++)
                    lg[cf] = 2.0f * acc[a][cf][r] - sqv[cf];
                float tm = fmaxf(fmaxf(lg[0], lg[1]), fmaxf(lg[2], lg[3]));
                float mn = fmaxf(m[a][r], tm);
                float al = __expf(m[a][r] - mn);
                m[a][r] = mn;
                float p[4];
                #pragma unroll
                for (int cf = 0; cf < 4; cf++) p[cf] = __expf(lg[cf] - mn);
                l[a][r] = l[a][r] * al + ((p[0] + p[1]) + (p[2] + p[3]));
                float sm = 0.f;
                #pragma unroll
                for (int cf = 0; cf < 4; cf++)
                    sm += ((mb[a][r] >> cf) & 1u) ? p[cf] : 0.f;
                s[a][r] = s[a][r] * al + sm;
            }

        // 6. write staged tile t+1 into the other buffer (vmcnt covered above)
        if (t < NTILES - 1) {
            #pragma unroll
            for (int it = 0; it < 4; it++) {
                int q = it * 16 + sq_;
                *reinterpret_cast<uint4*>(
                    &ldsB[cur ^ 1][q * D + ((sg_ ^ (q & 15)) * 8)]) = stg[it];
            }
        }

        // 7. one barrier per tile; nothing outstanding -> drain is free
        __syncthreads();
        simi_p += CT;
    }

    // end: cross-lane (lo group, 16 lanes) max + rescale + sum, once
    #pragma unroll
    for (int a = 0; a < 2; a++)
        #pragma unroll
        for (int r = 0; r < 4; r++) {
            float M = m[a][r];
            #pragma unroll
            for (int off = 1; off < 16; off <<= 1)
                M = fmaxf(M, __shfl_xor(M, off));
            float sc = __expf(m[a][r] - M);
            float L = l[a][r] * sc, S = s[a][r] * sc;
            #pragma unroll
            for (int off = 1; off < 16; off <<= 1) {
                L += __shfl_xor(L, off);
                S += __shfl_xor(S, off);
            }
            if (lo == 0) {
                int row = rbase + a * 16 + hi * 4 + r;
                int idx = chunk * N + row;
                pm[idx] = M; pl[idx] = L; ps[idx] = S;
            }
        }

    // negative count: wave reduce -> LDS -> one plain store per block
    #pragma unroll
    for (int off = 1; off < 64; off <<= 1) cnt += __shfl_xor(cnt, off);
    if (lane == 0) cred[wave] = cnt;
    __syncthreads();
    if (tid == 0)
        blockcnt[blockIdx.y * 64 + blockIdx.x] = cred[0] + cred[1] + cred[2] + cred[3];
}

// Merge per-chunk (m,l,s) partials per row; accumulate sum of s/l and the
// negative count (from 1024 per-block partials). 64 atomics total.
__global__ void merge_kernel(const float* __restrict__ pm, const float* __restrict__ pl,
                             const float* __restrict__ ps, const uint32* __restrict__ blockcnt,
                             float* __restrict__ s_acc, uint32* __restrict__ neg_acc) {
    const int row = blockIdx.x * 256 + threadIdx.x;
    float M = -1e30f;
    #pragma unroll
    for (int k = 0; k < NCHUNK; k++) M = fmaxf(M, pm[k * N + row]);
    float L = 0.f, S = 0.f;
    #pragma unroll
    for (int k = 0; k < NCHUNK; k++) {
        float e = __expf(pm[k * N + row] - M);
        L += pl[k * N + row] * e;
        S += ps[k * N + row] * e;
    }
    float r = S / L;
    uint32 pc = (threadIdx.x < 32) ? blockcnt[blockIdx.x * 32 + threadIdx.x] : 0u;
    #pragma unroll
    for (int off = 32; off > 0; off >>= 1) {
        r  += __shfl_xor(r, off);
        pc += __shfl_xor(pc, off);
    }
    __shared__ float red[4];
    __shared__ uint32 redp[4];
    int lane = threadIdx.x & 63, w = threadIdx.x >> 6;
    if (lane == 0) { red[w] = r; redp[w] = pc; }
    __syncthreads();
    if (threadIdx.x == 0) {
        atomicAdd(s_acc, red[0] + red[1] + red[2] + red[3]);
        atomicAdd(neg_acc, redp[0] + redp[1] + redp[2] + redp[3]);
    }
}

__global__ void final_kernel(const float* __restrict__ s_acc, const uint32* __restrict__ neg_acc,
                             float* __restrict__ out) {
    double S = (double)s_acc[0];
    double C = (double)neg_acc[0];   // count(simi != 1), counted directly
    double n = (double)N;
    out[0] = (float)((2.0 * S + C - n) / (n * n));
}

extern "C" void kernel_launch(void* const* d_in, const int* in_sizes, int n_in,
                              void* d_out, int out_size, void* d_ws, size_t ws_size,
                              hipStream_t stream) {
    const float* f1   = (const float*)d_in[0];
    const float* f2   = (const float*)d_in[1];
    const int*   simi = (const int*)d_in[2];
    float* out = (float*)d_out;
    char* ws = (char*)d_ws;

    float*  acc_s    = (float*)(ws + OFF_ACC);
    uint32* acc_n    = (uint32*)(ws + OFF_ACC + 4);
    float*  sq2      = (float*)(ws + OFF_SQ2);
    uint32* blockcnt = (uint32*)(ws + OFF_BCNT);
    float*  pm       = (float*)(ws + OFF_M);
    float*  pl       = (float*)(ws + OFF_L);
    float*  ps       = (float*)(ws + OFF_S);
    unsigned short* f1b = (unsigned short*)(ws + OFF_F1);
    unsigned short* f2b = (unsigned short*)(ws + OFF_F2);

    hipMemsetAsync(ws + OFF_ACC, 0, 64, stream);
    prep_kernel<<<256, 256, 0, stream>>>(f1, f2, f1b, f2b, sq2);
    main_kernel<<<dim3(N / RT, NCHUNK), 256, 0, stream>>>(f1b, f2b, sq2, simi,
                                                          pm, pl, ps, blockcnt);
    merge_kernel<<<N / 256, 256, 0, stream>>>(pm, pl, ps, blockcnt, acc_s, acc_n);
    final_kernel<<<1, 1, 0, stream>>>(acc_s, acc_n, out);
}

// Round 3
// 382.891 us; speedup vs baseline: 1.1665x; 1.0199x over previous
//
#include <hip/hip_runtime.h>
#include <hip/hip_bf16.h>
#include <stdint.h>

#define N 8192
#define D 128
#define NCHUNK 16
#define CHUNK (N / NCHUNK)      // 512 cols per chunk
#define RT 128                  // rows per block (4 waves x 32)
#define CT 64                   // cols per LDS tile
#define NTILES (CHUNK / CT)     // 8
#define NBLK (N / RT * NCHUNK)  // 1024 main blocks

#define LOG2E     1.4426950408889634f
#define TWO_LOG2E 2.8853900817779268f

typedef short bf16x8 __attribute__((ext_vector_type(8)));
typedef float f32x4 __attribute__((ext_vector_type(4)));
typedef int   i32x4 __attribute__((ext_vector_type(4)));
typedef unsigned int uint32;

#define AS1 __attribute__((address_space(1)))
#define AS3 __attribute__((address_space(3)))

// ---- workspace layout (bytes) ----
#define OFF_ACC   0u                          // [0] float S_sum, [4] uint32 C_count
#define OFF_SQ2   1024u                       // 8192 floats
#define OFF_BCNT  (OFF_SQ2 + N * 4u)          // NBLK uint32 per-block negative counts
#define OFF_M     (OFF_BCNT + NBLK * 4u)      // NCHUNK*N floats (per-chunk row max, log2-space)
#define OFF_L     (OFF_M + NCHUNK * N * 4u)
#define OFF_S     (OFF_L + NCHUNK * N * 4u)
#define OFF_F1    (OFF_S + NCHUNK * N * 4u)   // feat1 bf16
#define OFF_F2    (OFF_F1 + N * D * 2u)       // feat2 bf16

// Convert feats to bf16; compute sq2[j] = ||feat2_j||^2. float2/ushort2 form.
__global__ __launch_bounds__(256)
void prep_kernel(const float* __restrict__ f1, const float* __restrict__ f2,
                 unsigned short* __restrict__ f1b, unsigned short* __restrict__ f2b,
                 float* __restrict__ sq2) {
    const int w    = blockIdx.x * 4 + (threadIdx.x >> 6);  // 0..1023
    const int lane = threadIdx.x & 63;
    for (int row = w; row < N; row += 1024) {
        float2 a = *reinterpret_cast<const float2*>(f1 + row * D + 2 * lane);
        float2 b = *reinterpret_cast<const float2*>(f2 + row * D + 2 * lane);
        __hip_bfloat16 a0 = __float2bfloat16(a.x), a1 = __float2bfloat16(a.y);
        __hip_bfloat16 b0 = __float2bfloat16(b.x), b1 = __float2bfloat16(b.y);
        ushort2 ua = make_ushort2(*(unsigned short*)&a0, *(unsigned short*)&a1);
        ushort2 ub = make_ushort2(*(unsigned short*)&b0, *(unsigned short*)&b1);
        *reinterpret_cast<ushort2*>(f1b + row * D + 2 * lane) = ua;
        *reinterpret_cast<ushort2*>(f2b + row * D + 2 * lane) = ub;
        float ss = b.x * b.x + b.y * b.y;
        #pragma unroll
        for (int off = 32; off > 0; off >>= 1) ss += __shfl_xor(ss, off);
        if (lane == 0) sq2[row] = ss;
    }
}

// FUSED: GEMM + online softmax (log2-space) + raw-simi masking + neg count.
// R3 pipeline — ZERO mid-tile vmcnt waits:
//   - simi prefetched ONE TILE AHEAD: issued in tile t, consumed (convert) at
//     the top of tile t+1, where the previous barrier already drained it.
//   - B staged via global_load_lds (width 16) with PRE-SWIZZLED global source:
//     wave w / iter it covers LDS rows q=16it+4w+hi; lane (hi,lo) fetches
//     col c=16w+4hi+it, chunk sg=lo^(4w+hi) — identical LDS content to the
//     verified register-staged XOR layout, but linear LDS dests and no VGPRs.
//   - sq2 (pre-scaled by log2e) staged to LDS once: softmax reads it via
//     ds_read (broadcast pattern, conflict-free) — no vmcnt in the queue.
//   The only VMEM drain is the end-of-tile barrier; everything outstanding
//   there (simi t+1, staging t+1) had a full tile (~3000 cyc) to complete.
//   sched_barrier(0) pins the prefetch issues above the MFMA cluster so the
//   scheduler cannot sink them toward the barrier.
__global__ __launch_bounds__(256)
void main_kernel(const unsigned short* __restrict__ f1b,
                 const unsigned short* __restrict__ f2b,
                 const float* __restrict__ sq2,
                 const int* __restrict__ simi,
                 float* __restrict__ pm, float* __restrict__ pl, float* __restrict__ ps,
                 uint32* __restrict__ blockcnt) {
    __shared__ unsigned short ldsB[2][CT * D];  // 2 x 16 KB, XOR-swizzled content
    __shared__ float sq2l[CHUNK];               // 2 KB, pre-scaled by log2e
    __shared__ uint32 cred[4];

    const int tid  = threadIdx.x;
    const int wave = tid >> 6;
    const int lane = tid & 63;
    const int lo   = lane & 15;
    const int hi   = lane >> 4;

    const int rowtile = blockIdx.x;       // 0..63
    const int chunk   = blockIdx.y;       // 0..15
    const int rbase   = rowtile * RT + wave * 32;
    const int cbase0  = chunk * CHUNK;

    // A fragments: 2 sets of 16 rows, full K=128, resident for the sweep.
    bf16x8 afrag[2][4];
    #pragma unroll
    for (int a = 0; a < 2; a++) {
        const unsigned short* ap = f1b + (size_t)(rbase + a * 16 + lo) * D + hi * 8;
        #pragma unroll
        for (int kk = 0; kk < 4; kk++)
            afrag[a][kk] = *reinterpret_cast<const bf16x8*>(ap + kk * 32);
    }

    // staging constants (pre-swizzled global source for global_load_lds)
    const int whi = wave * 4 + hi;        // 0..15 (== q & 15 for our rows)
    const int sgx = lo ^ whi;             // source 16B chunk index

    // simi base: rows rbase+hi*4 (+a*16+r), cols cbase0 + 4*lo
    const int* simi_p = simi + (size_t)(rbase + hi * 4) * N + cbase0 + 4 * lo;

    // per-lane online-softmax state (log2-space); negative count
    float m[2][4], l[2][4], s[2][4];
    #pragma unroll
    for (int a = 0; a < 2; a++)
        #pragma unroll
        for (int r = 0; r < 4; r++) { m[a][r] = -1e30f; l[a][r] = 0.f; s[a][r] = 0.f; }
    uint32 cnt = 0;

    // ---- prologue: stage B tile 0 (glds), simi tile 0, sq2 -> LDS ----
    #pragma unroll
    for (int it = 0; it < 4; it++) {
        const unsigned short* gp =
            f2b + (size_t)(cbase0 + 16 * wave + 4 * hi + it) * D + sgx * 8;
        unsigned short* lp = &ldsB[0][(it * 16 + wave * 4) * D];
        __builtin_amdgcn_global_load_lds((const AS1 void*)gp, (AS3 void*)lp, 16, 0, 0);
    }
    i32x4 mkv[2][4];
    #pragma unroll
    for (int a = 0; a < 2; a++)
        #pragma unroll
        for (int r = 0; r < 4; r++)
            mkv[a][r] = __builtin_nontemporal_load(
                reinterpret_cast<const i32x4*>(simi_p + (size_t)(a * 16 + r) * N));
    #pragma unroll
    for (int i = 0; i < 2; i++)
        sq2l[tid + i * 256] = LOG2E * sq2[cbase0 + tid + i * 256];
    __syncthreads();   // drains everything: tile-0 data resident

    for (int t = 0; t < NTILES; t++) {
        const int cur = t & 1;

        // 1. convert tile t's simi (arrived: drained by previous barrier)
        uint32 mb[2][4];
        #pragma unroll
        for (int a = 0; a < 2; a++)
            #pragma unroll
            for (int r = 0; r < 4; r++) {
                i32x4 v = mkv[a][r];
                uint32 nib = (uint32)(v[0] == 1) | ((uint32)(v[1] == 1) << 1) |
                             ((uint32)(v[2] == 1) << 2) | ((uint32)(v[3] == 1) << 3);
                mb[a][r] = nib;
                cnt += 4u - __popc(nib);
            }

        // 2. prefetch tile t+1: simi -> mkv, B -> buf[cur^1] via glds
        if (t < NTILES - 1) {
            const int* sp = simi_p + (size_t)(t + 1) * CT;
            #pragma unroll
            for (int a = 0; a < 2; a++)
                #pragma unroll
                for (int r = 0; r < 4; r++)
                    mkv[a][r] = __builtin_nontemporal_load(
                        reinterpret_cast<const i32x4*>(sp + (size_t)(a * 16 + r) * N));
            const int cb_n = cbase0 + (t + 1) * CT;
            #pragma unroll
            for (int it = 0; it < 4; it++) {
                const unsigned short* gp =
                    f2b + (size_t)(cb_n + 16 * wave + 4 * hi + it) * D + sgx * 8;
                unsigned short* lp = &ldsB[cur ^ 1][(it * 16 + wave * 4) * D];
                __builtin_amdgcn_global_load_lds((const AS1 void*)gp, (AS3 void*)lp, 16, 0, 0);
            }
        }
        // pin the prefetch issues above the compute cluster
        __builtin_amdgcn_sched_barrier(0);

        // 3. MFMA: 32 rows x 64 cols from buf[cur] (lgkmcnt only)
        f32x4 acc[2][4];
        #pragma unroll
        for (int cf = 0; cf < 4; cf++) {
            acc[0][cf] = (f32x4){0.f, 0.f, 0.f, 0.f};
            acc[1][cf] = (f32x4){0.f, 0.f, 0.f, 0.f};
            const int brow = cf * 16 + lo;
            #pragma unroll
            for (int kk = 0; kk < 4; kk++) {
                int g = kk * 4 + hi;
                bf16x8 b = *reinterpret_cast<const bf16x8*>(
                    &ldsB[cur][brow * D + ((g ^ (brow & 15)) * 8)]);
                acc[0][cf] = __builtin_amdgcn_mfma_f32_16x16x32_bf16(afrag[0][kk], b, acc[0][cf], 0, 0, 0);
                acc[1][cf] = __builtin_amdgcn_mfma_f32_16x16x32_bf16(afrag[1][kk], b, acc[1][cf], 0, 0, 0);
            }
        }

        // 4. softmax in log2-space: lg' = (2*log2e)*c - sq2*log2e; p = exp2
        f32x4 sqv = *reinterpret_cast<const f32x4*>(&sq2l[t * CT + 4 * lo]);
        #pragma unroll
        for (int a = 0; a < 2; a++)
            #pragma unroll
            for (int r = 0; r < 4; r++) {
                float lg[4];
                #pragma unroll
                for (int cf = 0; cf < 4; cf++)
                    lg[cf] = TWO_LOG2E * acc[a][cf][r] - sqv[cf];
                float tm = fmaxf(fmaxf(lg[0], lg[1]), fmaxf(lg[2], lg[3]));
                float mn = fmaxf(m[a][r], tm);
                float al = __builtin_amdgcn_exp2f(m[a][r] - mn);
                m[a][r] = mn;
                float p[4];
                #pragma unroll
                for (int cf = 0; cf < 4; cf++)
                    p[cf] = __builtin_amdgcn_exp2f(lg[cf] - mn);
                l[a][r] = l[a][r] * al + ((p[0] + p[1]) + (p[2] + p[3]));
                float sm = 0.f;
                #pragma unroll
                for (int cf = 0; cf < 4; cf++)
                    sm += ((mb[a][r] >> cf) & 1u) ? p[cf] : 0.f;
                s[a][r] = s[a][r] * al + sm;
            }

        // 5. barrier: everything outstanding had a full tile to land
        if (t < NTILES - 1) __syncthreads();
    }

    // end: cross-lane (lo group, 16 lanes) max + rescale + sum, once
    #pragma unroll
    for (int a = 0; a < 2; a++)
        #pragma unroll
        for (int r = 0; r < 4; r++) {
            float M = m[a][r];
            #pragma unroll
            for (int off = 1; off < 16; off <<= 1)
                M = fmaxf(M, __shfl_xor(M, off));
            float sc = __builtin_amdgcn_exp2f(m[a][r] - M);
            float L = l[a][r] * sc, S = s[a][r] * sc;
            #pragma unroll
            for (int off = 1; off < 16; off <<= 1) {
                L += __shfl_xor(L, off);
                S += __shfl_xor(S, off);
            }
            if (lo == 0) {
                int row = rbase + a * 16 + hi * 4 + r;
                int idx = chunk * N + row;
                pm[idx] = M; pl[idx] = L; ps[idx] = S;
            }
        }

    // negative count: wave reduce -> LDS -> one plain store per block
    #pragma unroll
    for (int off = 1; off < 64; off <<= 1) cnt += __shfl_xor(cnt, off);
    if (lane == 0) cred[wave] = cnt;
    __syncthreads();
    if (tid == 0)
        blockcnt[blockIdx.y * 64 + blockIdx.x] = cred[0] + cred[1] + cred[2] + cred[3];
}

// Merge per-chunk (m,l,s) partials per row (log2-space); accumulate sum of
// s/l and the negative count (from 1024 per-block partials). 64 atomics.
__global__ void merge_kernel(const float* __restrict__ pm, const float* __restrict__ pl,
                             const float* __restrict__ ps, const uint32* __restrict__ blockcnt,
                             float* __restrict__ s_acc, uint32* __restrict__ neg_acc) {
    const int row = blockIdx.x * 256 + threadIdx.x;
    float M = -1e30f;
    #pragma unroll
    for (int k = 0; k < NCHUNK; k++) M = fmaxf(M, pm[k * N + row]);
    float L = 0.f, S = 0.f;
    #pragma unroll
    for (int k = 0; k < NCHUNK; k++) {
        float e = __builtin_amdgcn_exp2f(pm[k * N + row] - M);
        L += pl[k * N + row] * e;
        S += ps[k * N + row] * e;
    }
    float r = S / L;
    uint32 pc = (threadIdx.x < 32) ? blockcnt[blockIdx.x * 32 + threadIdx.x] : 0u;
    #pragma unroll
    for (int off = 32; off > 0; off >>= 1) {
        r  += __shfl_xor(r, off);
        pc += __shfl_xor(pc, off);
    }
    __shared__ float red[4];
    __shared__ uint32 redp[4];
    int lane = threadIdx.x & 63, w = threadIdx.x >> 6;
    if (lane == 0) { red[w] = r; redp[w] = pc; }
    __syncthreads();
    if (threadIdx.x == 0) {
        atomicAdd(s_acc, red[0] + red[1] + red[2] + red[3]);
        atomicAdd(neg_acc, redp[0] + redp[1] + redp[2] + redp[3]);
    }
}

__global__ void final_kernel(const float* __restrict__ s_acc, const uint32* __restrict__ neg_acc,
                             float* __restrict__ out) {
    double S = (double)s_acc[0];
    double C = (double)neg_acc[0];   // count(simi != 1), counted directly
    double n = (double)N;
    out[0] = (float)((2.0 * S + C - n) / (n * n));
}

extern "C" void kernel_launch(void* const* d_in, const int* in_sizes, int n_in,
                              void* d_out, int out_size, void* d_ws, size_t ws_size,
                              hipStream_t stream) {
    const float* f1   = (const float*)d_in[0];
    const float* f2   = (const float*)d_in[1];
    const int*   simi = (const int*)d_in[2];
    float* out = (float*)d_out;
    char* ws = (char*)d_ws;

    float*  acc_s    = (float*)(ws + OFF_ACC);
    uint32* acc_n    = (uint32*)(ws + OFF_ACC + 4);
    float*  sq2      = (float*)(ws + OFF_SQ2);
    uint32* blockcnt = (uint32*)(ws + OFF_BCNT);
    float*  pm       = (float*)(ws + OFF_M);
    float*  pl       = (float*)(ws + OFF_L);
    float*  ps       = (float*)(ws + OFF_S);
    unsigned short* f1b = (unsigned short*)(ws + OFF_F1);
    unsigned short* f2b = (unsigned short*)(ws + OFF_F2);

    hipMemsetAsync(ws + OFF_ACC, 0, 64, stream);
    prep_kernel<<<256, 256, 0, stream>>>(f1, f2, f1b, f2b, sq2);
    main_kernel<<<dim3(N / RT, NCHUNK), 256, 0, stream>>>(f1b, f2b, sq2, simi,
                                                          pm, pl, ps, blockcnt);
    merge_kernel<<<N / 256, 256, 0, stream>>>(pm, pl, ps, blockcnt, acc_s, acc_n);
    final_kernel<<<1, 1, 0, stream>>>(acc_s, acc_n, out);
}